// Round 1
// baseline (549.675 us; speedup 1.0000x reference)
//
#include <hip/hip_runtime.h>
#include <hip/hip_bf16.h>
#include <stdint.h>

#define B_     16
#define T_     128
#define L_     100
#define IN_    100
#define EMB_   100
#define FEAT_  400
#define HID_   128
#define OUT_   50
#define RNNIN_ 500
#define VOCAB_ 10002
#define BT_    2048
#define G4_    512

__device__ __forceinline__ float b2f(unsigned short u) {
    union { unsigned int i; float f; } v; v.i = ((unsigned int)u) << 16; return v.f;
}
__device__ __forceinline__ float fast_tanh(float x) {
    x = fminf(15.f, fmaxf(-15.f, x));
    float e = __expf(2.f * x);
    return (e - 1.f) * __builtin_amdgcn_rcpf(e + 1.f);
}
__device__ __forceinline__ float sigm(float x) {
    x = fminf(30.f, fmaxf(-30.f, x));
    float e = __expf(-x);
    return __builtin_amdgcn_rcpf(1.f + e);
}

// C[r][j] = sum_i A[r][i] * Wt[wrow+i][j]  (+bias[j]), j<400, K=100
// 32 rows/block, 256 threads: jj=tid&63 col-lane, rr=tid>>6; 8 rows x up-to-7 cols each.
template<int BF16OUT>
__global__ __launch_bounds__(256) void table_gemm(
    const float* __restrict__ A, int lda, int rows,
    const float* __restrict__ Wt, int wrow,
    const float* __restrict__ bias, void* __restrict__ outp)
{
    __shared__ float As[32][100];
    int r0 = blockIdx.x * 32, tid = threadIdx.x;
    for (int i = tid; i < 3200; i += 256) {
        int r = i / 100, c = i - r * 100;
        int gr = r0 + r;
        As[r][c] = (gr < rows) ? A[(size_t)gr * lda + c] : 0.f;
    }
    __syncthreads();
    int jj = tid & 63, rr = tid >> 6;
    float acc[8][7];
#pragma unroll
    for (int k = 0; k < 8; k++)
#pragma unroll
        for (int m = 0; m < 7; m++) acc[k][m] = 0.f;
    for (int i = 0; i < 100; i++) {
        float w[7];
#pragma unroll
        for (int m = 0; m < 7; m++) {
            int j = jj + (m << 6);
            w[m] = (j < 400) ? Wt[(size_t)(wrow + i) * 400 + j] : 0.f;
        }
#pragma unroll
        for (int k = 0; k < 8; k++) {
            float a = As[rr * 8 + k][i];   // wave-uniform -> LDS broadcast
#pragma unroll
            for (int m = 0; m < 7; m++) acc[k][m] = fmaf(a, w[m], acc[k][m]);
        }
    }
#pragma unroll
    for (int k = 0; k < 8; k++) {
        int gr = r0 + rr * 8 + k;
        if (gr >= rows) continue;
#pragma unroll
        for (int m = 0; m < 7; m++) {
            int j = jj + (m << 6);
            if (j >= 400) continue;
            float v = acc[k][m];
            if (bias) v += bias[j];
            if (BF16OUT) ((__hip_bfloat16*)outp)[(size_t)gr * 400 + j] = __float2bfloat16(v);
            else         ((float*)outp)[(size_t)gr * 400 + j] = v;
        }
    }
}

__global__ void f32_to_bf16_k(const float* __restrict__ in, __hip_bfloat16* __restrict__ out, int n) {
    for (int i = blockIdx.x * 256 + threadIdx.x; i < n; i += gridDim.x * 256)
        out[i] = __float2bfloat16(in[i]);
}

__global__ void transpose_rc(const float* __restrict__ in, float* __restrict__ out, int R, int C) {
    int n = R * C;
    for (int i = blockIdx.x * 256 + threadIdx.x; i < n; i += gridDim.x * 256) {
        int r = i / C, c = i - r * C;
        out[(size_t)c * R + r] = in[i];
    }
}

// ctx[bt][l] = sum_j tanh(Es[i0][j]+Ee[i2][j]+Ep[i1][j]+q[bt][j]) * Wa[j]
__global__ __launch_bounds__(256) void stage_a(
    const float* __restrict__ x,
    const __hip_bfloat16* __restrict__ Es, const __hip_bfloat16* __restrict__ Ee,
    const __hip_bfloat16* __restrict__ Ep,
    const float* __restrict__ q, const float* __restrict__ Wa,
    float* __restrict__ ctx)
{
    __shared__ float qs[400], was[400];
    int bt = blockIdx.x, tid = threadIdx.x;
    for (int i = tid; i < 400; i += 256) { qs[i] = q[(size_t)bt * 400 + i]; was[i] = Wa[i]; }
    __syncthreads();
    int wave = tid >> 6, lane = tid & 63;
    const float* xr = x + (size_t)bt * 400 + 100;
    const float4* q4 = (const float4*)qs;
    const float4* w4 = (const float4*)was;
    for (int l = wave; l < 100; l += 4) {
        int i0 = (int)xr[3 * l], i1 = (int)xr[3 * l + 1], i2 = (int)xr[3 * l + 2];
        const ushort4* ps = (const ushort4*)(Es + (size_t)i0 * 400);
        const ushort4* pe = (const ushort4*)(Ee + (size_t)i2 * 400);
        const ushort4* pp = (const ushort4*)(Ep + (size_t)i1 * 400);
        float sum = 0.f;
        for (int g = lane; g < 100; g += 64) {
            ushort4 a = ps[g], b = pe[g], cc = pp[g];
            float4 qv = q4[g], wv = w4[g];
            float z0 = b2f(a.x) + b2f(b.x) + b2f(cc.x) + qv.x;
            float z1 = b2f(a.y) + b2f(b.y) + b2f(cc.y) + qv.y;
            float z2 = b2f(a.z) + b2f(b.z) + b2f(cc.z) + qv.z;
            float z3 = b2f(a.w) + b2f(b.w) + b2f(cc.w) + qv.w;
            sum = fmaf(fast_tanh(z0), wv.x, sum);
            sum = fmaf(fast_tanh(z1), wv.y, sum);
            sum = fmaf(fast_tanh(z2), wv.z, sum);
            sum = fmaf(fast_tanh(z3), wv.w, sum);
        }
#pragma unroll
        for (int off = 32; off; off >>= 1) sum += __shfl_xor(sum, off);
        if (lane == 0) ctx[(size_t)bt * 100 + l] = sum;
    }
}

// softmax over T (axis=1) for each (b,l). thread per (b,l) column.
__global__ void softmax_t(const float* __restrict__ ctx, float* __restrict__ attn) {
    int id = blockIdx.x * 256 + threadIdx.x;
    if (id >= B_ * L_) return;
    int b = id / 100, l = id - b * 100;
    const float* p = ctx + (size_t)b * 12800 + l;
    float* o = attn + (size_t)b * 12800 + l;
    float m = -1e30f;
    for (int t = 0; t < 128; t++) m = fmaxf(m, p[t * 100]);
    float s = 0.f;
    for (int t = 0; t < 128; t++) { float e = __expf(p[t * 100] - m); o[t * 100] = e; s += e; }
    float rs = 1.f / s;
    for (int t = 0; t < 128; t++) o[t * 100] *= rs;
}

// cv[bt] = [sum_l a*EN[i0], sum_l a*EN[i2], sum_l a*EP[i1], first*sum_l a]
__global__ __launch_bounds__(128) void stage_c(
    const float* __restrict__ x, const float* __restrict__ attn,
    const unsigned short* __restrict__ ENb, const unsigned short* __restrict__ EPb,
    float* __restrict__ cv)
{
    __shared__ float at[100];
    __shared__ int idx[300];
    int bt = blockIdx.x, tid = threadIdx.x;
    if (tid < 100) at[tid] = attn[(size_t)bt * 100 + tid];
    const float* xr = x + (size_t)bt * 400 + 100;
    for (int i = tid; i < 300; i += 128) idx[i] = (int)xr[i];
    __syncthreads();
    int d = tid;
    if (d < 100) {
        float as = 0.f, ae = 0.f, ap = 0.f, sa = 0.f;
        for (int l = 0; l < 100; l++) {
            float a = at[l]; sa += a;
            as = fmaf(a, b2f(ENb[(size_t)idx[3 * l] * 100 + d]), as);
            ae = fmaf(a, b2f(ENb[(size_t)idx[3 * l + 2] * 100 + d]), ae);
            ap = fmaf(a, b2f(EPb[(size_t)idx[3 * l + 1] * 100 + d]), ap);
        }
        float* o = cv + (size_t)bt * 400;
        o[d] = as; o[100 + d] = ae; o[200 + d] = ap;
        o[300 + d] = x[(size_t)bt * 400 + d] * sa;
    }
}

// X[bt][g] = b_ih[g]+b_hh[g] + sum_k rnn_in[bt][k]*Wih[g][k];  rnn_in=[first(100),cv(400)]
__global__ __launch_bounds__(512) void gemm_x(
    const float* __restrict__ x, const float* __restrict__ cv,
    const float* __restrict__ WihT, const float* __restrict__ bih,
    const float* __restrict__ bhh, float* __restrict__ X)
{
    __shared__ float ins[8][500];
    int r0 = blockIdx.x * 8, tid = threadIdx.x;
    for (int i = tid; i < 4000; i += 512) {
        int r = i / 500, k = i - r * 500;
        ins[r][k] = (k < 100) ? x[(size_t)(r0 + r) * 400 + k]
                              : cv[(size_t)(r0 + r) * 400 + (k - 100)];
    }
    __syncthreads();
    int g = tid;
    float acc[8];
#pragma unroll
    for (int r = 0; r < 8; r++) acc[r] = 0.f;
    for (int k4 = 0; k4 < 125; k4++) {
        int k = k4 * 4;
        float w0 = WihT[(size_t)k * 512 + g];
        float w1 = WihT[(size_t)(k + 1) * 512 + g];
        float w2 = WihT[(size_t)(k + 2) * 512 + g];
        float w3 = WihT[(size_t)(k + 3) * 512 + g];
#pragma unroll
        for (int r = 0; r < 8; r++) {
            float4 a = *(const float4*)&ins[r][k];
            acc[r] = fmaf(a.x, w0, fmaf(a.y, w1, fmaf(a.z, w2, fmaf(a.w, w3, acc[r]))));
        }
    }
    float bias = bih[g] + bhh[g];
#pragma unroll
    for (int r = 0; r < 8; r++) X[(size_t)(r0 + r) * 512 + g] = acc[r] + bias;
}

// one block per batch; thread g owns gate-row g (W_hh row in VGPRs), h broadcast via LDS.
__global__ __launch_bounds__(512) void lstm_k(
    const float* __restrict__ X, const float* __restrict__ WhhT, float* __restrict__ hs)
{
    int b = blockIdx.x, g = threadIdx.x;
    float w[128];
#pragma unroll
    for (int k = 0; k < 128; k++) w[k] = WhhT[(size_t)k * 512 + g];
    __shared__ float h_s[128];
    __shared__ float g_s[512];
    float c = 0.f;
    if (g < 128) h_s[g] = 0.f;
    __syncthreads();
    const float* xb = X + (size_t)b * 128 * 512;
    for (int t = 0; t < 128; t++) {
        float acc = 0.f;
        const float4* h4 = (const float4*)h_s;
#pragma unroll
        for (int qq = 0; qq < 32; qq++) {
            float4 hv = h4[qq];
            acc = fmaf(hv.x, w[4 * qq], acc);
            acc = fmaf(hv.y, w[4 * qq + 1], acc);
            acc = fmaf(hv.z, w[4 * qq + 2], acc);
            acc = fmaf(hv.w, w[4 * qq + 3], acc);
        }
        g_s[g] = acc;
        __syncthreads();
        if (g < 128) {
            const float* xt = xb + t * 512;
            float gi = xt[g] + g_s[g];
            float gf = xt[128 + g] + g_s[128 + g];
            float gc = xt[256 + g] + g_s[256 + g];
            float go = xt[384 + g] + g_s[384 + g];
            c = sigm(gf) * c + sigm(gi) * fast_tanh(gc);
            float hn = sigm(go) * fast_tanh(c);
            h_s[g] = hn;
            hs[((size_t)b * 128 + t) * 128 + g] = hn;
        }
        __syncthreads();
    }
}

__global__ __launch_bounds__(64) void fc_k(
    const float* __restrict__ hs, const float* __restrict__ Wfc,
    const float* __restrict__ bfc, float* __restrict__ out)
{
    int r0 = blockIdx.x * 4, o = threadIdx.x;
    if (o >= 50) return;
    float acc[4] = {0.f, 0.f, 0.f, 0.f};
    for (int j = 0; j < 128; j++) {
        float wv = Wfc[j * 50 + o];
#pragma unroll
        for (int r = 0; r < 4; r++)
            acc[r] = fmaf(hs[(size_t)(r0 + r) * 128 + j], wv, acc[r]);
    }
    float bb = bfc[o];
#pragma unroll
    for (int r = 0; r < 4; r++) out[(size_t)(r0 + r) * 50 + o] = sigm(acc[r] + bb);
}

extern "C" void kernel_launch(void* const* d_in, const int* in_sizes, int n_in,
                              void* d_out, int out_size, void* d_ws, size_t ws_size,
                              hipStream_t stream) {
    const float* x   = (const float*)d_in[0];
    const float* EN  = (const float*)d_in[1];
    const float* EP  = (const float*)d_in[2];
    const float* Wt  = (const float*)d_in[3];
    const float* bt  = (const float*)d_in[4];
    const float* Wa  = (const float*)d_in[5];
    // d_in[6] = b_a: constant shift along softmax axis -> cancels exactly, unused.
    const float* Wih = (const float*)d_in[7];
    const float* Whh = (const float*)d_in[8];
    const float* bih = (const float*)d_in[9];
    const float* bhh = (const float*)d_in[10];
    const float* Wfc = (const float*)d_in[11];
    const float* bfc = (const float*)d_in[12];
    float* out = (float*)d_out;

    char* ws = (char*)d_ws;
    size_t off = 0;
    auto alloc = [&](size_t bytes) -> char* {
        char* p = ws + off;
        off = (off + bytes + 255) & ~(size_t)255;
        return p;
    };
    __hip_bfloat16* Es  = (__hip_bfloat16*)alloc((size_t)VOCAB_ * 400 * 2);
    __hip_bfloat16* Ee  = (__hip_bfloat16*)alloc((size_t)VOCAB_ * 400 * 2);
    __hip_bfloat16* Epb = (__hip_bfloat16*)alloc((size_t)VOCAB_ * 400 * 2);
    __hip_bfloat16* ENb = (__hip_bfloat16*)alloc((size_t)VOCAB_ * 100 * 2);
    __hip_bfloat16* EPb = (__hip_bfloat16*)alloc((size_t)VOCAB_ * 100 * 2);
    float* q    = (float*)alloc((size_t)BT_ * 400 * 4);
    float* ctx  = (float*)alloc((size_t)BT_ * 100 * 4);
    float* attn = (float*)alloc((size_t)BT_ * 100 * 4);
    float* cv   = (float*)alloc((size_t)BT_ * 400 * 4);
    float* X    = (float*)alloc((size_t)BT_ * 512 * 4);
    float* hsb  = (float*)alloc((size_t)BT_ * 128 * 4);
    float* WihT = (float*)alloc((size_t)500 * 512 * 4);
    float* WhhT = (float*)alloc((size_t)128 * 512 * 4);

    int egrid = (VOCAB_ + 31) / 32;   // 313
    table_gemm<1><<<egrid, 256, 0, stream>>>(EN, 100, VOCAB_, Wt, 0,   nullptr, (void*)Es);
    table_gemm<1><<<egrid, 256, 0, stream>>>(EN, 100, VOCAB_, Wt, 100, nullptr, (void*)Ee);
    table_gemm<1><<<egrid, 256, 0, stream>>>(EP, 100, VOCAB_, Wt, 200, nullptr, (void*)Epb);
    table_gemm<0><<<BT_ / 32, 256, 0, stream>>>(x, 400, BT_, Wt, 300, bt, (void*)q);

    f32_to_bf16_k<<<512, 256, 0, stream>>>(EN, ENb, VOCAB_ * 100);
    f32_to_bf16_k<<<512, 256, 0, stream>>>(EP, EPb, VOCAB_ * 100);
    transpose_rc<<<256, 256, 0, stream>>>(Wih, WihT, 512, 500);
    transpose_rc<<<64, 256, 0, stream>>>(Whh, WhhT, 512, 128);

    stage_a<<<BT_, 256, 0, stream>>>(x, Es, Ee, Epb, q, Wa, ctx);
    softmax_t<<<(B_ * L_ + 255) / 256, 256, 0, stream>>>(ctx, attn);
    stage_c<<<BT_, 128, 0, stream>>>(x, attn, (const unsigned short*)ENb,
                                     (const unsigned short*)EPb, cv);
    gemm_x<<<BT_ / 8, 512, 0, stream>>>(x, cv, WihT, bih, bhh, X);
    lstm_k<<<B_, 512, 0, stream>>>(X, WhhT, hsb);
    fc_k<<<BT_ / 4, 64, 0, stream>>>(hsb, Wfc, bfc, out);
}

// Round 2
// 374.412 us; speedup vs baseline: 1.4681x; 1.4681x over previous
//
#include <hip/hip_runtime.h>
#include <hip/hip_bf16.h>
#include <stdint.h>

#define B_     16
#define T_     128
#define L_     100
#define IN_    100
#define EMB_   100
#define FEAT_  400
#define HID_   128
#define OUT_   50
#define RNNIN_ 500
#define VOCAB_ 10002
#define BT_    2048

__device__ __forceinline__ float lo2f(unsigned int u) {
    union { unsigned int i; float f; } v; v.i = u << 16; return v.f;
}
__device__ __forceinline__ float hi2f(unsigned int u) {
    union { unsigned int i; float f; } v; v.i = u & 0xffff0000u; return v.f;
}
__device__ __forceinline__ float fast_tanh(float x) {
    x = fminf(15.f, fmaxf(-15.f, x));
    float e = __expf(2.f * x);
    return (e - 1.f) * __builtin_amdgcn_rcpf(e + 1.f);
}
__device__ __forceinline__ float sigm(float x) {
    x = fminf(30.f, fmaxf(-30.f, x));
    float e = __expf(-x);
    return __builtin_amdgcn_rcpf(1.f + e);
}

// ---------- prep: bf16 casts + weight transposes, one launch ----------
__global__ void prep_k(const float* __restrict__ EN, const float* __restrict__ EP,
                       const float* __restrict__ Wih, const float* __restrict__ Whh,
                       __hip_bfloat16* __restrict__ ENb, __hip_bfloat16* __restrict__ EPb,
                       float* __restrict__ WihT, float* __restrict__ WhhT) {
    int t0 = blockIdx.x * 256 + threadIdx.x;
    int stride = gridDim.x * 256;
    int n1 = VOCAB_ * 100;
    for (int i = t0; i < n1; i += stride) ENb[i] = __float2bfloat16(EN[i]);
    for (int i = t0; i < n1; i += stride) EPb[i] = __float2bfloat16(EP[i]);
    for (int i = t0; i < 512 * 500; i += stride) {
        int r = i / 500, c = i - r * 500;
        WihT[(size_t)c * 512 + r] = Wih[i];
    }
    for (int i = t0; i < 512 * 128; i += stride) {
        int r = i / 128, c = i - r * 128;
        WhhT[(size_t)c * 512 + r] = Whh[i];
    }
}

// ---------- C[r][j] = sum_i A[r][i] * Wt[wrow+i][j], 32 rows/block ----------
__device__ __forceinline__ void table_gemm_body(
    const float* __restrict__ A, int lda, int rows,
    const float* __restrict__ Wt, int wrow,
    const float* __restrict__ bias, void* __restrict__ outp, int bf16out, int r0)
{
    __shared__ float As[32][100];
    int tid = threadIdx.x;
    for (int i = tid; i < 3200; i += 256) {
        int r = i / 100, c = i - r * 100;
        int gr = r0 + r;
        As[r][c] = (gr < rows) ? A[(size_t)gr * lda + c] : 0.f;
    }
    __syncthreads();
    int jj = tid & 63, rr = tid >> 6;
    float acc[8][7];
#pragma unroll
    for (int k = 0; k < 8; k++)
#pragma unroll
        for (int m = 0; m < 7; m++) acc[k][m] = 0.f;
    for (int i = 0; i < 100; i++) {
        float w[7];
#pragma unroll
        for (int m = 0; m < 7; m++) {
            int j = jj + (m << 6);
            w[m] = (j < 400) ? Wt[(size_t)(wrow + i) * 400 + j] : 0.f;
        }
#pragma unroll
        for (int k = 0; k < 8; k++) {
            float a = As[rr * 8 + k][i];
#pragma unroll
            for (int m = 0; m < 7; m++) acc[k][m] = fmaf(a, w[m], acc[k][m]);
        }
    }
#pragma unroll
    for (int k = 0; k < 8; k++) {
        int gr = r0 + rr * 8 + k;
        if (gr >= rows) continue;
#pragma unroll
        for (int m = 0; m < 7; m++) {
            int j = jj + (m << 6);
            if (j >= 400) continue;
            float v = acc[k][m];
            if (bias) v += bias[j];
            if (bf16out) ((__hip_bfloat16*)outp)[(size_t)gr * 400 + j] = __float2bfloat16(v);
            else         ((float*)outp)[(size_t)gr * 400 + j] = v;
        }
    }
}

__global__ __launch_bounds__(256) void table_gemm3(
    const float* __restrict__ EN, const float* __restrict__ EP,
    const float* __restrict__ Wt,
    __hip_bfloat16* __restrict__ Es, __hip_bfloat16* __restrict__ Ee,
    __hip_bfloat16* __restrict__ Epb)
{
    int which = blockIdx.y;
    const float* A = (which == 2) ? EP : EN;
    __hip_bfloat16* o = (which == 0) ? Es : ((which == 1) ? Ee : Epb);
    table_gemm_body(A, 100, VOCAB_, Wt, which * 100, nullptr, (void*)o, 1, blockIdx.x * 32);
}

__global__ __launch_bounds__(256) void table_gemm_q(
    const float* __restrict__ x, const float* __restrict__ Wt,
    const float* __restrict__ bias, float* __restrict__ q)
{
    table_gemm_body(x, 400, BT_, Wt, 300, bias, (void*)q, 0, blockIdx.x * 32);
}

// ---------- stage A: ctx[bt][l] = sum_j tanh(Es+Ee+Ep+q)*Wa ----------
__global__ __launch_bounds__(256) void stage_a(
    const float* __restrict__ x,
    const __hip_bfloat16* __restrict__ Es, const __hip_bfloat16* __restrict__ Ee,
    const __hip_bfloat16* __restrict__ Ep,
    const float* __restrict__ q, const float* __restrict__ Wa,
    float* __restrict__ ctx)
{
    __shared__ int idx_s[300];
    int bt = blockIdx.x, tid = threadIdx.x;
    const float* xr = x + (size_t)bt * 400 + 100;
    for (int i = tid; i < 300; i += 256) idx_s[i] = (int)xr[i];
    int lane = tid & 63, wave = tid >> 6;
    bool act = lane < 50;
    int j0 = lane * 8;
    float qv[8], wv[8];
    if (act) {
        float4 qa = *(const float4*)(q + (size_t)bt * 400 + j0);
        float4 qb = *(const float4*)(q + (size_t)bt * 400 + j0 + 4);
        float4 wa = *(const float4*)(Wa + j0);
        float4 wb = *(const float4*)(Wa + j0 + 4);
        qv[0]=qa.x; qv[1]=qa.y; qv[2]=qa.z; qv[3]=qa.w;
        qv[4]=qb.x; qv[5]=qb.y; qv[6]=qb.z; qv[7]=qb.w;
        wv[0]=wa.x; wv[1]=wa.y; wv[2]=wa.z; wv[3]=wa.w;
        wv[4]=wb.x; wv[5]=wb.y; wv[6]=wb.z; wv[7]=wb.w;
    } else {
#pragma unroll
        for (int jj = 0; jj < 8; jj++) { qv[jj] = 0.f; wv[jj] = 0.f; }
    }
    __syncthreads();
    for (int l = wave; l < 100; l += 4) {
        int i0 = idx_s[3 * l], i1 = idx_s[3 * l + 1], i2 = idx_s[3 * l + 2];
        float sum = 0.f;
        if (act) {
            uint4 a  = *((const uint4*)(Es + (size_t)i0 * 400) + lane);
            uint4 b  = *((const uint4*)(Ee + (size_t)i2 * 400) + lane);
            uint4 cc = *((const uint4*)(Ep + (size_t)i1 * 400) + lane);
            float z;
            z = lo2f(a.x)+lo2f(b.x)+lo2f(cc.x)+qv[0]; sum = fmaf(fast_tanh(z), wv[0], sum);
            z = hi2f(a.x)+hi2f(b.x)+hi2f(cc.x)+qv[1]; sum = fmaf(fast_tanh(z), wv[1], sum);
            z = lo2f(a.y)+lo2f(b.y)+lo2f(cc.y)+qv[2]; sum = fmaf(fast_tanh(z), wv[2], sum);
            z = hi2f(a.y)+hi2f(b.y)+hi2f(cc.y)+qv[3]; sum = fmaf(fast_tanh(z), wv[3], sum);
            z = lo2f(a.z)+lo2f(b.z)+lo2f(cc.z)+qv[4]; sum = fmaf(fast_tanh(z), wv[4], sum);
            z = hi2f(a.z)+hi2f(b.z)+hi2f(cc.z)+qv[5]; sum = fmaf(fast_tanh(z), wv[5], sum);
            z = lo2f(a.w)+lo2f(b.w)+lo2f(cc.w)+qv[6]; sum = fmaf(fast_tanh(z), wv[6], sum);
            z = hi2f(a.w)+hi2f(b.w)+hi2f(cc.w)+qv[7]; sum = fmaf(fast_tanh(z), wv[7], sum);
        }
#pragma unroll
        for (int off = 32; off; off >>= 1) sum += __shfl_xor(sum, off);
        if (lane == 0) ctx[(size_t)bt * 100 + l] = sum;
    }
}

// ---------- softmax over T: one wave per (b,l) ----------
__global__ __launch_bounds__(256) void softmax_w(
    const float* __restrict__ ctx, float* __restrict__ attn)
{
    int wid = blockIdx.x * 4 + (threadIdx.x >> 6);   // 0..1599
    int lane = threadIdx.x & 63;
    int b = wid / 100, l = wid - b * 100;
    size_t base = (size_t)b * 128 * 100 + l;
    float v0 = ctx[base + (size_t)lane * 100];
    float v1 = ctx[base + (size_t)(lane + 64) * 100];
    float m = fmaxf(v0, v1);
#pragma unroll
    for (int off = 32; off; off >>= 1) m = fmaxf(m, __shfl_xor(m, off));
    float e0 = __expf(v0 - m), e1 = __expf(v1 - m);
    float s = e0 + e1;
#pragma unroll
    for (int off = 32; off; off >>= 1) s += __shfl_xor(s, off);
    float rs = 1.f / s;
    attn[base + (size_t)lane * 100] = e0 * rs;
    attn[base + (size_t)(lane + 64) * 100] = e1 * rs;
}

// ---------- stage C: weighted re-gather of raw embeddings ----------
__global__ __launch_bounds__(128) void stage_c(
    const float* __restrict__ x, const float* __restrict__ attn,
    const unsigned short* __restrict__ ENb, const unsigned short* __restrict__ EPb,
    float* __restrict__ cv)
{
    __shared__ float at[100];
    __shared__ int idx[300];
    int bt = blockIdx.x, tid = threadIdx.x;
    if (tid < 100) at[tid] = attn[(size_t)bt * 100 + tid];
    const float* xr = x + (size_t)bt * 400 + 100;
    for (int i = tid; i < 300; i += 128) idx[i] = (int)xr[i];
    __syncthreads();
    int d = tid;
    if (d < 100) {
        float as = 0.f, ae = 0.f, ap = 0.f, sa = 0.f;
#pragma unroll 4
        for (int l = 0; l < 100; l++) {
            float a = at[l]; sa += a;
            as = fmaf(a, lo2f((unsigned)ENb[(size_t)idx[3 * l] * 100 + d] << 0) * 0.f + lo2f((unsigned)ENb[(size_t)idx[3 * l] * 100 + d]), as);
            ae = fmaf(a, lo2f((unsigned)ENb[(size_t)idx[3 * l + 2] * 100 + d]), ae);
            ap = fmaf(a, lo2f((unsigned)EPb[(size_t)idx[3 * l + 1] * 100 + d]), ap);
        }
        float* o = cv + (size_t)bt * 400;
        o[d] = as; o[100 + d] = ae; o[200 + d] = ap;
        o[300 + d] = x[(size_t)bt * 400 + d] * sa;
    }
}

// ---------- X = rnn_in @ Wih.T + biases ----------
__global__ __launch_bounds__(512) void gemm_x(
    const float* __restrict__ x, const float* __restrict__ cv,
    const float* __restrict__ WihT, const float* __restrict__ bih,
    const float* __restrict__ bhh, float* __restrict__ X)
{
    __shared__ float ins[8][500];
    int r0 = blockIdx.x * 8, tid = threadIdx.x;
    for (int i = tid; i < 4000; i += 512) {
        int r = i / 500, k = i - r * 500;
        ins[r][k] = (k < 100) ? x[(size_t)(r0 + r) * 400 + k]
                              : cv[(size_t)(r0 + r) * 400 + (k - 100)];
    }
    __syncthreads();
    int g = tid;
    float acc[8];
#pragma unroll
    for (int r = 0; r < 8; r++) acc[r] = 0.f;
    for (int k4 = 0; k4 < 125; k4++) {
        int k = k4 * 4;
        float w0 = WihT[(size_t)k * 512 + g];
        float w1 = WihT[(size_t)(k + 1) * 512 + g];
        float w2 = WihT[(size_t)(k + 2) * 512 + g];
        float w3 = WihT[(size_t)(k + 3) * 512 + g];
#pragma unroll
        for (int r = 0; r < 8; r++) {
            float4 a = *(const float4*)&ins[r][k];
            acc[r] = fmaf(a.x, w0, fmaf(a.y, w1, fmaf(a.z, w2, fmaf(a.w, w3, acc[r]))));
        }
    }
    float bias = bih[g] + bhh[g];
#pragma unroll
    for (int r = 0; r < 8; r++) X[(size_t)(r0 + r) * 512 + g] = acc[r] + bias;
}

// ---------- LSTM: one block/batch; w resident in VGPRs; distributed activations ----------
__global__ __launch_bounds__(512, 1) void lstm_k(
    const float* __restrict__ X, const float* __restrict__ WhhT, float* __restrict__ hs)
{
    int b = blockIdx.x, g = threadIdx.x;
    int gq = g >> 7;               // 0:i 1:f 2:g 3:o — wave-uniform
    float w[128];
#pragma unroll
    for (int k = 0; k < 128; k++) w[k] = WhhT[(size_t)k * 512 + g];
    __shared__ float h_s[128];
    __shared__ float p_s[512];
    float c = 0.f;
    if (g < 128) h_s[g] = 0.f;
    const float* xb = X + (size_t)b * 128 * 512;
    float xpre = xb[g];
    __syncthreads();
    for (int t = 0; t < 128; t++) {
        float a0 = 0.f, a1 = 0.f, a2 = 0.f, a3 = 0.f;
        const float4* h4 = (const float4*)h_s;
#pragma unroll
        for (int qq = 0; qq < 32; qq++) {
            float4 hv = h4[qq];
            a0 = fmaf(hv.x, w[4 * qq], a0);
            a1 = fmaf(hv.y, w[4 * qq + 1], a1);
            a2 = fmaf(hv.z, w[4 * qq + 2], a2);
            a3 = fmaf(hv.w, w[4 * qq + 3], a3);
        }
        float acc = (a0 + a1) + (a2 + a3) + xpre;
        float post = (gq == 2) ? fast_tanh(acc) : sigm(acc);
        p_s[g] = post;
        if (t < 127) xpre = xb[(size_t)(t + 1) * 512 + g];
        __syncthreads();
        if (g < 128) {
            float pi = p_s[g], pf = p_s[128 + g], pg = p_s[256 + g], po = p_s[384 + g];
            c = pf * c + pi * pg;
            float hn = po * fast_tanh(c);
            h_s[g] = hn;
            hs[((size_t)b * 128 + t) * 128 + g] = hn;
        }
        __syncthreads();
    }
}

__global__ __launch_bounds__(64) void fc_k(
    const float* __restrict__ hs, const float* __restrict__ Wfc,
    const float* __restrict__ bfc, float* __restrict__ out)
{
    int r0 = blockIdx.x * 4, o = threadIdx.x;
    if (o >= 50) return;
    float acc[4] = {0.f, 0.f, 0.f, 0.f};
    for (int j = 0; j < 128; j++) {
        float wv = Wfc[j * 50 + o];
#pragma unroll
        for (int r = 0; r < 4; r++)
            acc[r] = fmaf(hs[(size_t)(r0 + r) * 128 + j], wv, acc[r]);
    }
    float bb = bfc[o];
#pragma unroll
    for (int r = 0; r < 4; r++) out[(size_t)(r0 + r) * 50 + o] = sigm(acc[r] + bb);
}

extern "C" void kernel_launch(void* const* d_in, const int* in_sizes, int n_in,
                              void* d_out, int out_size, void* d_ws, size_t ws_size,
                              hipStream_t stream) {
    const float* x   = (const float*)d_in[0];
    const float* EN  = (const float*)d_in[1];
    const float* EP  = (const float*)d_in[2];
    const float* Wt  = (const float*)d_in[3];
    const float* bt  = (const float*)d_in[4];
    const float* Wa  = (const float*)d_in[5];
    // d_in[6] = b_a: uniform shift along the softmax axis -> cancels, unused.
    const float* Wih = (const float*)d_in[7];
    const float* Whh = (const float*)d_in[8];
    const float* bih = (const float*)d_in[9];
    const float* bhh = (const float*)d_in[10];
    const float* Wfc = (const float*)d_in[11];
    const float* bfc = (const float*)d_in[12];
    float* out = (float*)d_out;

    char* ws = (char*)d_ws;
    size_t off = 0;
    auto alloc = [&](size_t bytes) -> char* {
        char* p = ws + off;
        off = (off + bytes + 255) & ~(size_t)255;
        return p;
    };
    __hip_bfloat16* Es  = (__hip_bfloat16*)alloc((size_t)VOCAB_ * 400 * 2);
    __hip_bfloat16* Ee  = (__hip_bfloat16*)alloc((size_t)VOCAB_ * 400 * 2);
    __hip_bfloat16* Epb = (__hip_bfloat16*)alloc((size_t)VOCAB_ * 400 * 2);
    __hip_bfloat16* ENb = (__hip_bfloat16*)alloc((size_t)VOCAB_ * 100 * 2);
    __hip_bfloat16* EPb = (__hip_bfloat16*)alloc((size_t)VOCAB_ * 100 * 2);
    float* q    = (float*)alloc((size_t)BT_ * 400 * 4);
    float* ctx  = (float*)alloc((size_t)BT_ * 100 * 4);
    float* attn = (float*)alloc((size_t)BT_ * 100 * 4);
    float* cv   = (float*)alloc((size_t)BT_ * 400 * 4);
    float* X    = (float*)alloc((size_t)BT_ * 512 * 4);
    float* hsb  = (float*)alloc((size_t)BT_ * 128 * 4);
    float* WihT = (float*)alloc((size_t)500 * 512 * 4);
    float* WhhT = (float*)alloc((size_t)128 * 512 * 4);

    prep_k<<<1024, 256, 0, stream>>>(EN, EP, Wih, Whh, ENb, EPb, WihT, WhhT);
    int egrid = (VOCAB_ + 31) / 32;   // 313
    table_gemm3<<<dim3(egrid, 3), 256, 0, stream>>>(EN, EP, Wt, Es, Ee, Epb);
    table_gemm_q<<<BT_ / 32, 256, 0, stream>>>(x, Wt, bt, q);

    stage_a<<<BT_, 256, 0, stream>>>(x, Es, Ee, Epb, q, Wa, ctx);
    softmax_w<<<400, 256, 0, stream>>>(ctx, attn);
    stage_c<<<BT_, 128, 0, stream>>>(x, attn, (const unsigned short*)ENb,
                                     (const unsigned short*)EPb, cv);
    gemm_x<<<BT_ / 8, 512, 0, stream>>>(x, cv, WihT, bih, bhh, X);
    lstm_k<<<B_, 512, 0, stream>>>(X, WhhT, hsb);
    fc_k<<<BT_ / 4, 64, 0, stream>>>(hsb, Wfc, bfc, out);
}

// Round 3
// 370.596 us; speedup vs baseline: 1.4832x; 1.0103x over previous
//
#include <hip/hip_runtime.h>
#include <hip/hip_bf16.h>
#include <stdint.h>

#define B_     16
#define T_     128
#define L_     100
#define IN_    100
#define EMB_   100
#define FEAT_  400
#define HID_   128
#define OUT_   50
#define RNNIN_ 500
#define VOCAB_ 10002
#define BT_    2048

typedef __attribute__((ext_vector_type(8))) short short8;
typedef __attribute__((ext_vector_type(4))) float f32x4;

__device__ __forceinline__ float lo2f(unsigned int u) {
    union { unsigned int i; float f; } v; v.i = u << 16; return v.f;
}
__device__ __forceinline__ float hi2f(unsigned int u) {
    union { unsigned int i; float f; } v; v.i = u & 0xffff0000u; return v.f;
}
__device__ __forceinline__ float fast_tanh(float x) {
    x = fminf(15.f, fmaxf(-15.f, x));
    float e = __expf(2.f * x);
    return (e - 1.f) * __builtin_amdgcn_rcpf(e + 1.f);
}
__device__ __forceinline__ float sigm(float x) {
    x = fminf(30.f, fmaxf(-30.f, x));
    float e = __expf(-x);
    return __builtin_amdgcn_rcpf(1.f + e);
}

// ---------- prep: bf16 casts (EN, EP, Whh) + Wih transpose, one launch ----------
__global__ void prep_k(const float* __restrict__ EN, const float* __restrict__ EP,
                       const float* __restrict__ Wih, const float* __restrict__ Whh,
                       __hip_bfloat16* __restrict__ ENb, __hip_bfloat16* __restrict__ EPb,
                       float* __restrict__ WihT, __hip_bfloat16* __restrict__ Whh_bf) {
    int t0 = blockIdx.x * 256 + threadIdx.x;
    int stride = gridDim.x * 256;
    int n1 = VOCAB_ * 100;
    for (int i = t0; i < n1; i += stride) ENb[i] = __float2bfloat16(EN[i]);
    for (int i = t0; i < n1; i += stride) EPb[i] = __float2bfloat16(EP[i]);
    for (int i = t0; i < 512 * 500; i += stride) {
        int r = i / 500, c = i - r * 500;
        WihT[(size_t)c * 512 + r] = Wih[i];
    }
    for (int i = t0; i < 512 * 128; i += stride) Whh_bf[i] = __float2bfloat16(Whh[i]);
}

// ---------- C[r][j] = sum_i A[r][i] * Wt[wrow+i][j], 32 rows/block ----------
__device__ __forceinline__ void table_gemm_body(
    const float* __restrict__ A, int lda, int rows,
    const float* __restrict__ Wt, int wrow,
    const float* __restrict__ bias, void* __restrict__ outp, int bf16out, int r0)
{
    __shared__ float As[32][100];
    int tid = threadIdx.x;
    for (int i = tid; i < 3200; i += 256) {
        int r = i / 100, c = i - r * 100;
        int gr = r0 + r;
        As[r][c] = (gr < rows) ? A[(size_t)gr * lda + c] : 0.f;
    }
    __syncthreads();
    int jj = tid & 63, rr = tid >> 6;
    float acc[8][7];
#pragma unroll
    for (int k = 0; k < 8; k++)
#pragma unroll
        for (int m = 0; m < 7; m++) acc[k][m] = 0.f;
    for (int i = 0; i < 100; i++) {
        float w[7];
#pragma unroll
        for (int m = 0; m < 7; m++) {
            int j = jj + (m << 6);
            w[m] = (j < 400) ? Wt[(size_t)(wrow + i) * 400 + j] : 0.f;
        }
#pragma unroll
        for (int k = 0; k < 8; k++) {
            float a = As[rr * 8 + k][i];
#pragma unroll
            for (int m = 0; m < 7; m++) acc[k][m] = fmaf(a, w[m], acc[k][m]);
        }
    }
#pragma unroll
    for (int k = 0; k < 8; k++) {
        int gr = r0 + rr * 8 + k;
        if (gr >= rows) continue;
#pragma unroll
        for (int m = 0; m < 7; m++) {
            int j = jj + (m << 6);
            if (j >= 400) continue;
            float v = acc[k][m];
            if (bias) v += bias[j];
            if (bf16out) ((__hip_bfloat16*)outp)[(size_t)gr * 400 + j] = __float2bfloat16(v);
            else         ((float*)outp)[(size_t)gr * 400 + j] = v;
        }
    }
}

__global__ __launch_bounds__(256) void table_gemm3(
    const float* __restrict__ EN, const float* __restrict__ EP,
    const float* __restrict__ Wt,
    __hip_bfloat16* __restrict__ Es, __hip_bfloat16* __restrict__ Ee,
    __hip_bfloat16* __restrict__ Epb)
{
    int which = blockIdx.y;
    const float* A = (which == 2) ? EP : EN;
    __hip_bfloat16* o = (which == 0) ? Es : ((which == 1) ? Ee : Epb);
    table_gemm_body(A, 100, VOCAB_, Wt, which * 100, nullptr, (void*)o, 1, blockIdx.x * 32);
}

__global__ __launch_bounds__(256) void table_gemm_q(
    const float* __restrict__ x, const float* __restrict__ Wt,
    const float* __restrict__ bias, float* __restrict__ q)
{
    table_gemm_body(x, 400, BT_, Wt, 300, bias, (void*)q, 0, blockIdx.x * 32);
}

// ---------- stage A: ctx[bt][l] = sum_j tanh(Es+Ee+Ep+q)*Wa ----------
__global__ __launch_bounds__(256) void stage_a(
    const float* __restrict__ x,
    const __hip_bfloat16* __restrict__ Es, const __hip_bfloat16* __restrict__ Ee,
    const __hip_bfloat16* __restrict__ Ep,
    const float* __restrict__ q, const float* __restrict__ Wa,
    float* __restrict__ ctx)
{
    __shared__ int idx_s[300];
    int bt = blockIdx.x, tid = threadIdx.x;
    const float* xr = x + (size_t)bt * 400 + 100;
    for (int i = tid; i < 300; i += 256) idx_s[i] = (int)xr[i];
    int lane = tid & 63, wave = tid >> 6;
    bool act = lane < 50;
    int j0 = lane * 8;
    float qv[8], wv[8];
    if (act) {
        float4 qa = *(const float4*)(q + (size_t)bt * 400 + j0);
        float4 qb = *(const float4*)(q + (size_t)bt * 400 + j0 + 4);
        float4 wa = *(const float4*)(Wa + j0);
        float4 wb = *(const float4*)(Wa + j0 + 4);
        qv[0]=qa.x; qv[1]=qa.y; qv[2]=qa.z; qv[3]=qa.w;
        qv[4]=qb.x; qv[5]=qb.y; qv[6]=qb.z; qv[7]=qb.w;
        wv[0]=wa.x; wv[1]=wa.y; wv[2]=wa.z; wv[3]=wa.w;
        wv[4]=wb.x; wv[5]=wb.y; wv[6]=wb.z; wv[7]=wb.w;
    } else {
#pragma unroll
        for (int jj = 0; jj < 8; jj++) { qv[jj] = 0.f; wv[jj] = 0.f; }
    }
    __syncthreads();
    for (int l = wave; l < 100; l += 4) {
        int i0 = idx_s[3 * l], i1 = idx_s[3 * l + 1], i2 = idx_s[3 * l + 2];
        float sum = 0.f;
        if (act) {
            uint4 a  = *((const uint4*)(Es + (size_t)i0 * 400) + lane);
            uint4 b  = *((const uint4*)(Ee + (size_t)i2 * 400) + lane);
            uint4 cc = *((const uint4*)(Ep + (size_t)i1 * 400) + lane);
            float z;
            z = lo2f(a.x)+lo2f(b.x)+lo2f(cc.x)+qv[0]; sum = fmaf(fast_tanh(z), wv[0], sum);
            z = hi2f(a.x)+hi2f(b.x)+hi2f(cc.x)+qv[1]; sum = fmaf(fast_tanh(z), wv[1], sum);
            z = lo2f(a.y)+lo2f(b.y)+lo2f(cc.y)+qv[2]; sum = fmaf(fast_tanh(z), wv[2], sum);
            z = hi2f(a.y)+hi2f(b.y)+hi2f(cc.y)+qv[3]; sum = fmaf(fast_tanh(z), wv[3], sum);
            z = lo2f(a.z)+lo2f(b.z)+lo2f(cc.z)+qv[4]; sum = fmaf(fast_tanh(z), wv[4], sum);
            z = hi2f(a.z)+hi2f(b.z)+hi2f(cc.z)+qv[5]; sum = fmaf(fast_tanh(z), wv[5], sum);
            z = lo2f(a.w)+lo2f(b.w)+lo2f(cc.w)+qv[6]; sum = fmaf(fast_tanh(z), wv[6], sum);
            z = hi2f(a.w)+hi2f(b.w)+hi2f(cc.w)+qv[7]; sum = fmaf(fast_tanh(z), wv[7], sum);
        }
#pragma unroll
        for (int off = 32; off; off >>= 1) sum += __shfl_xor(sum, off);
        if (lane == 0) ctx[(size_t)bt * 100 + l] = sum;
    }
}

// ---------- softmax over T: one wave per (b,l) ----------
__global__ __launch_bounds__(256) void softmax_w(
    const float* __restrict__ ctx, float* __restrict__ attn)
{
    int wid = blockIdx.x * 4 + (threadIdx.x >> 6);   // 0..1599
    int lane = threadIdx.x & 63;
    int b = wid / 100, l = wid - b * 100;
    size_t base = (size_t)b * 128 * 100 + l;
    float v0 = ctx[base + (size_t)lane * 100];
    float v1 = ctx[base + (size_t)(lane + 64) * 100];
    float m = fmaxf(v0, v1);
#pragma unroll
    for (int off = 32; off; off >>= 1) m = fmaxf(m, __shfl_xor(m, off));
    float e0 = __expf(v0 - m), e1 = __expf(v1 - m);
    float s = e0 + e1;
#pragma unroll
    for (int off = 32; off; off >>= 1) s += __shfl_xor(s, off);
    float rs = 1.f / s;
    attn[base + (size_t)lane * 100] = e0 * rs;
    attn[base + (size_t)(lane + 64) * 100] = e1 * rs;
}

// ---------- stage C: weighted re-gather of raw embeddings ----------
__global__ __launch_bounds__(128) void stage_c(
    const float* __restrict__ x, const float* __restrict__ attn,
    const unsigned short* __restrict__ ENb, const unsigned short* __restrict__ EPb,
    float* __restrict__ cv)
{
    __shared__ float at[100];
    __shared__ int idx[300];
    int bt = blockIdx.x, tid = threadIdx.x;
    if (tid < 100) at[tid] = attn[(size_t)bt * 100 + tid];
    const float* xr = x + (size_t)bt * 400 + 100;
    for (int i = tid; i < 300; i += 128) idx[i] = (int)xr[i];
    __syncthreads();
    int d = tid;
    if (d < 100) {
        float as = 0.f, ae = 0.f, ap = 0.f, sa = 0.f;
#pragma unroll 4
        for (int l = 0; l < 100; l++) {
            float a = at[l]; sa += a;
            as = fmaf(a, lo2f(ENb[(size_t)idx[3 * l] * 100 + d]), as);
            ae = fmaf(a, lo2f(ENb[(size_t)idx[3 * l + 2] * 100 + d]), ae);
            ap = fmaf(a, lo2f(EPb[(size_t)idx[3 * l + 1] * 100 + d]), ap);
        }
        float* o = cv + (size_t)bt * 400;
        o[d] = as; o[100 + d] = ae; o[200 + d] = ap;
        o[300 + d] = x[(size_t)bt * 400 + d] * sa;
    }
}

// ---------- X = rnn_in @ Wih.T + biases ----------
__global__ __launch_bounds__(512) void gemm_x(
    const float* __restrict__ x, const float* __restrict__ cv,
    const float* __restrict__ WihT, const float* __restrict__ bih,
    const float* __restrict__ bhh, float* __restrict__ X)
{
    __shared__ float ins[8][500];
    int r0 = blockIdx.x * 8, tid = threadIdx.x;
    for (int i = tid; i < 4000; i += 512) {
        int r = i / 500, k = i - r * 500;
        ins[r][k] = (k < 100) ? x[(size_t)(r0 + r) * 400 + k]
                              : cv[(size_t)(r0 + r) * 400 + (k - 100)];
    }
    __syncthreads();
    int g = tid;
    float acc[8];
#pragma unroll
    for (int r = 0; r < 8; r++) acc[r] = 0.f;
    for (int k4 = 0; k4 < 125; k4++) {
        int k = k4 * 4;
        float w0 = WihT[(size_t)k * 512 + g];
        float w1 = WihT[(size_t)(k + 1) * 512 + g];
        float w2 = WihT[(size_t)(k + 2) * 512 + g];
        float w3 = WihT[(size_t)(k + 3) * 512 + g];
#pragma unroll
        for (int r = 0; r < 8; r++) {
            float4 a = *(const float4*)&ins[r][k];
            acc[r] = fmaf(a.x, w0, fmaf(a.y, w1, fmaf(a.z, w2, fmaf(a.w, w3, acc[r]))));
        }
    }
    float bias = bih[g] + bhh[g];
#pragma unroll
    for (int r = 0; r < 8; r++) X[(size_t)(r0 + r) * 512 + g] = acc[r] + bias;
}

// ---------- LSTM via MFMA: h(1x128) @ Whh^T(128x512) per step ----------
// 8 waves; wave w owns cols [w*64, w*64+64) = 4 tiles of 16.
// B-frag (bf16 Whh, row-major): lane holds Whh[g][kk*32 + kg*8 + j], g=w*64+n*16+col.
// A-frag: row 0 = h (lanes with col==0), rows 1-15 zero. D row 0 -> lanes 0-15, acc[0].
__global__ __launch_bounds__(512, 1) void lstm_k(
    const float* __restrict__ X, const __hip_bfloat16* __restrict__ Whh_bf,
    float* __restrict__ hs)
{
    int b = blockIdx.x, tid = threadIdx.x;
    int wave = tid >> 6, lane = tid & 63;
    int col = lane & 15, kg = lane >> 4;

    short8 bf[4][4];
#pragma unroll
    for (int n = 0; n < 4; n++) {
        int g = wave * 64 + n * 16 + col;
#pragma unroll
        for (int kk = 0; kk < 4; kk++)
            bf[n][kk] = *(const short8*)(Whh_bf + (size_t)g * 128 + kk * 32 + kg * 8);
    }

    __shared__ __hip_bfloat16 h_bf[128];
    __shared__ float p_s[512];
    float c = 0.f;
    if (tid < 128) h_bf[tid] = __float2bfloat16(0.f);

    const float* xb = X + (size_t)b * 128 * 512;
    float xq[4];
    if (lane < 16) {
#pragma unroll
        for (int n = 0; n < 4; n++) xq[n] = xb[wave * 64 + n * 16 + lane];
    }
    __syncthreads();

    for (int t = 0; t < 128; t++) {
        // A-fragments from h_bf (row 0 only)
        short8 af[4];
        short8 zz = {};
#pragma unroll
        for (int kk = 0; kk < 4; kk++) {
            af[kk] = zz;
            if (col == 0) af[kk] = *(const short8*)(h_bf + kk * 32 + kg * 8);
        }
        f32x4 acc[4];
#pragma unroll
        for (int n = 0; n < 4; n++) acc[n] = (f32x4){0.f, 0.f, 0.f, 0.f};
#pragma unroll
        for (int kk = 0; kk < 4; kk++)
#pragma unroll
            for (int n = 0; n < 4; n++)
                acc[n] = __builtin_amdgcn_mfma_f32_16x16x32_bf16(af[kk], bf[n][kk], acc[n], 0, 0, 0);

        if (lane < 16) {
#pragma unroll
            for (int n = 0; n < 4; n++) {
                int g = wave * 64 + n * 16 + lane;
                float pre = acc[n][0] + xq[n];
                float post = ((g >> 7) == 2) ? fast_tanh(pre) : sigm(pre);
                p_s[g] = post;
            }
            if (t < 127) {
#pragma unroll
                for (int n = 0; n < 4; n++)
                    xq[n] = xb[(size_t)(t + 1) * 512 + wave * 64 + n * 16 + lane];
            }
        }
        __syncthreads();
        if (tid < 128) {
            float pi = p_s[tid], pf = p_s[128 + tid], pg = p_s[256 + tid], po = p_s[384 + tid];
            c = pf * c + pi * pg;
            float hn = po * fast_tanh(c);
            hs[((size_t)b * 128 + t) * 128 + tid] = hn;
            h_bf[tid] = __float2bfloat16(hn);
        }
        __syncthreads();
    }
}

__global__ __launch_bounds__(64) void fc_k(
    const float* __restrict__ hs, const float* __restrict__ Wfc,
    const float* __restrict__ bfc, float* __restrict__ out)
{
    int r0 = blockIdx.x * 4, o = threadIdx.x;
    if (o >= 50) return;
    float acc[4] = {0.f, 0.f, 0.f, 0.f};
    for (int j = 0; j < 128; j++) {
        float wv = Wfc[j * 50 + o];
#pragma unroll
        for (int r = 0; r < 4; r++)
            acc[r] = fmaf(hs[(size_t)(r0 + r) * 128 + j], wv, acc[r]);
    }
    float bb = bfc[o];
#pragma unroll
    for (int r = 0; r < 4; r++) out[(size_t)(r0 + r) * 50 + o] = sigm(acc[r] + bb);
}

extern "C" void kernel_launch(void* const* d_in, const int* in_sizes, int n_in,
                              void* d_out, int out_size, void* d_ws, size_t ws_size,
                              hipStream_t stream) {
    const float* x   = (const float*)d_in[0];
    const float* EN  = (const float*)d_in[1];
    const float* EP  = (const float*)d_in[2];
    const float* Wt  = (const float*)d_in[3];
    const float* bt  = (const float*)d_in[4];
    const float* Wa  = (const float*)d_in[5];
    // d_in[6] = b_a: uniform shift along the softmax axis -> cancels, unused.
    const float* Wih = (const float*)d_in[7];
    const float* Whh = (const float*)d_in[8];
    const float* bih = (const float*)d_in[9];
    const float* bhh = (const float*)d_in[10];
    const float* Wfc = (const float*)d_in[11];
    const float* bfc = (const float*)d_in[12];
    float* out = (float*)d_out;

    char* ws = (char*)d_ws;
    size_t off = 0;
    auto alloc = [&](size_t bytes) -> char* {
        char* p = ws + off;
        off = (off + bytes + 255) & ~(size_t)255;
        return p;
    };
    __hip_bfloat16* Es  = (__hip_bfloat16*)alloc((size_t)VOCAB_ * 400 * 2);
    __hip_bfloat16* Ee  = (__hip_bfloat16*)alloc((size_t)VOCAB_ * 400 * 2);
    __hip_bfloat16* Epb = (__hip_bfloat16*)alloc((size_t)VOCAB_ * 400 * 2);
    __hip_bfloat16* ENb = (__hip_bfloat16*)alloc((size_t)VOCAB_ * 100 * 2);
    __hip_bfloat16* EPb = (__hip_bfloat16*)alloc((size_t)VOCAB_ * 100 * 2);
    float* q    = (float*)alloc((size_t)BT_ * 400 * 4);
    float* ctx  = (float*)alloc((size_t)BT_ * 100 * 4);
    float* attn = (float*)alloc((size_t)BT_ * 100 * 4);
    float* cv   = (float*)alloc((size_t)BT_ * 400 * 4);
    float* X    = (float*)alloc((size_t)BT_ * 512 * 4);
    float* hsb  = (float*)alloc((size_t)BT_ * 128 * 4);
    float* WihT = (float*)alloc((size_t)500 * 512 * 4);
    __hip_bfloat16* Whh_bf = (__hip_bfloat16*)alloc((size_t)512 * 128 * 2);

    prep_k<<<1024, 256, 0, stream>>>(EN, EP, Wih, Whh, ENb, EPb, WihT, Whh_bf);
    int egrid = (VOCAB_ + 31) / 32;   // 313
    table_gemm3<<<dim3(egrid, 3), 256, 0, stream>>>(EN, EP, Wt, Es, Ee, Epb);
    table_gemm_q<<<BT_ / 32, 256, 0, stream>>>(x, Wt, bt, q);

    stage_a<<<BT_, 256, 0, stream>>>(x, Es, Ee, Epb, q, Wa, ctx);
    softmax_w<<<400, 256, 0, stream>>>(ctx, attn);
    stage_c<<<BT_, 128, 0, stream>>>(x, attn, (const unsigned short*)ENb,
                                     (const unsigned short*)EPb, cv);
    gemm_x<<<BT_ / 8, 512, 0, stream>>>(x, cv, WihT, bih, bhh, X);
    lstm_k<<<B_, 512, 0, stream>>>(X, Whh_bf, hsb);
    fc_k<<<BT_ / 4, 64, 0, stream>>>(hsb, Wfc, bfc, out);
}

// Round 4
// 339.045 us; speedup vs baseline: 1.6212x; 1.0931x over previous
//
#include <hip/hip_runtime.h>
#include <hip/hip_bf16.h>
#include <stdint.h>

#define B_     16
#define T_     128
#define L_     100
#define IN_    100
#define EMB_   100
#define FEAT_  400
#define HID_   128
#define OUT_   50
#define RNNIN_ 500
#define VOCAB_ 10002
#define BT_    2048

typedef __attribute__((ext_vector_type(8))) short short8;
typedef __attribute__((ext_vector_type(4))) float f32x4;

__device__ __forceinline__ float lo2f(unsigned int u) {
    union { unsigned int i; float f; } v; v.i = u << 16; return v.f;
}
__device__ __forceinline__ float hi2f(unsigned int u) {
    union { unsigned int i; float f; } v; v.i = u & 0xffff0000u; return v.f;
}
__device__ __forceinline__ float fast_tanh(float x) {
    x = fminf(15.f, fmaxf(-15.f, x));
    float e = __expf(2.f * x);
    return (e - 1.f) * __builtin_amdgcn_rcpf(e + 1.f);
}
__device__ __forceinline__ float sigm(float x) {
    x = fminf(30.f, fmaxf(-30.f, x));
    float e = __expf(-x);
    return __builtin_amdgcn_rcpf(1.f + e);
}

// ---------- prep: bf16 casts (EN, EP, Whh) + Wih transpose, one launch ----------
__global__ void prep_k(const float* __restrict__ EN, const float* __restrict__ EP,
                       const float* __restrict__ Wih, const float* __restrict__ Whh,
                       __hip_bfloat16* __restrict__ ENb, __hip_bfloat16* __restrict__ EPb,
                       float* __restrict__ WihT, __hip_bfloat16* __restrict__ Whh_bf) {
    int t0 = blockIdx.x * 256 + threadIdx.x;
    int stride = gridDim.x * 256;
    int n1 = VOCAB_ * 100;
    for (int i = t0; i < n1; i += stride) ENb[i] = __float2bfloat16(EN[i]);
    for (int i = t0; i < n1; i += stride) EPb[i] = __float2bfloat16(EP[i]);
    for (int i = t0; i < 512 * 500; i += stride) {
        int r = i / 500, c = i - r * 500;
        WihT[(size_t)c * 512 + r] = Wih[i];
    }
    for (int i = t0; i < 512 * 128; i += stride) Whh_bf[i] = __float2bfloat16(Whh[i]);
}

// ---------- C[r][j] = sum_i A[r][i] * Wt[wrow+i][j], 32 rows/block ----------
__device__ __forceinline__ void table_gemm_body(
    const float* __restrict__ A, int lda, int rows,
    const float* __restrict__ Wt, int wrow,
    const float* __restrict__ bias, void* __restrict__ outp, int bf16out, int r0)
{
    __shared__ float As[32][100];
    int tid = threadIdx.x;
    for (int i = tid; i < 3200; i += 256) {
        int r = i / 100, c = i - r * 100;
        int gr = r0 + r;
        As[r][c] = (gr < rows) ? A[(size_t)gr * lda + c] : 0.f;
    }
    __syncthreads();
    int jj = tid & 63, rr = tid >> 6;
    float acc[8][7];
#pragma unroll
    for (int k = 0; k < 8; k++)
#pragma unroll
        for (int m = 0; m < 7; m++) acc[k][m] = 0.f;
    for (int i = 0; i < 100; i++) {
        float w[7];
#pragma unroll
        for (int m = 0; m < 7; m++) {
            int j = jj + (m << 6);
            w[m] = (j < 400) ? Wt[(size_t)(wrow + i) * 400 + j] : 0.f;
        }
#pragma unroll
        for (int k = 0; k < 8; k++) {
            float a = As[rr * 8 + k][i];
#pragma unroll
            for (int m = 0; m < 7; m++) acc[k][m] = fmaf(a, w[m], acc[k][m]);
        }
    }
#pragma unroll
    for (int k = 0; k < 8; k++) {
        int gr = r0 + rr * 8 + k;
        if (gr >= rows) continue;
#pragma unroll
        for (int m = 0; m < 7; m++) {
            int j = jj + (m << 6);
            if (j >= 400) continue;
            float v = acc[k][m];
            if (bias) v += bias[j];
            if (bf16out) ((__hip_bfloat16*)outp)[(size_t)gr * 400 + j] = __float2bfloat16(v);
            else         ((float*)outp)[(size_t)gr * 400 + j] = v;
        }
    }
}

__global__ __launch_bounds__(256) void table_gemm3(
    const float* __restrict__ EN, const float* __restrict__ EP,
    const float* __restrict__ Wt,
    __hip_bfloat16* __restrict__ Es, __hip_bfloat16* __restrict__ Ee,
    __hip_bfloat16* __restrict__ Epb)
{
    int which = blockIdx.y;
    const float* A = (which == 2) ? EP : EN;
    __hip_bfloat16* o = (which == 0) ? Es : ((which == 1) ? Ee : Epb);
    table_gemm_body(A, 100, VOCAB_, Wt, which * 100, nullptr, (void*)o, 1, blockIdx.x * 32);
}

__global__ __launch_bounds__(256) void table_gemm_q(
    const float* __restrict__ x, const float* __restrict__ Wt,
    const float* __restrict__ bias, float* __restrict__ q)
{
    table_gemm_body(x, 400, BT_, Wt, 300, bias, (void*)q, 0, blockIdx.x * 32);
}

// ---------- stage A: ctx[bt][l] = sum_j tanh(Es+Ee+Ep+q)*Wa ----------
__global__ __launch_bounds__(256) void stage_a(
    const float* __restrict__ x,
    const __hip_bfloat16* __restrict__ Es, const __hip_bfloat16* __restrict__ Ee,
    const __hip_bfloat16* __restrict__ Ep,
    const float* __restrict__ q, const float* __restrict__ Wa,
    float* __restrict__ ctx)
{
    __shared__ int idx_s[300];
    int bt = blockIdx.x, tid = threadIdx.x;
    const float* xr = x + (size_t)bt * 400 + 100;
    for (int i = tid; i < 300; i += 256) idx_s[i] = (int)xr[i];
    int lane = tid & 63, wave = tid >> 6;
    bool act = lane < 50;
    int j0 = lane * 8;
    float qv[8], wv[8];
    if (act) {
        float4 qa = *(const float4*)(q + (size_t)bt * 400 + j0);
        float4 qb = *(const float4*)(q + (size_t)bt * 400 + j0 + 4);
        float4 wa = *(const float4*)(Wa + j0);
        float4 wb = *(const float4*)(Wa + j0 + 4);
        qv[0]=qa.x; qv[1]=qa.y; qv[2]=qa.z; qv[3]=qa.w;
        qv[4]=qb.x; qv[5]=qb.y; qv[6]=qb.z; qv[7]=qb.w;
        wv[0]=wa.x; wv[1]=wa.y; wv[2]=wa.z; wv[3]=wa.w;
        wv[4]=wb.x; wv[5]=wb.y; wv[6]=wb.z; wv[7]=wb.w;
    } else {
#pragma unroll
        for (int jj = 0; jj < 8; jj++) { qv[jj] = 0.f; wv[jj] = 0.f; }
    }
    __syncthreads();
    for (int l = wave; l < 100; l += 4) {
        int i0 = idx_s[3 * l], i1 = idx_s[3 * l + 1], i2 = idx_s[3 * l + 2];
        float sum = 0.f;
        if (act) {
            uint4 a  = *((const uint4*)(Es + (size_t)i0 * 400) + lane);
            uint4 b  = *((const uint4*)(Ee + (size_t)i2 * 400) + lane);
            uint4 cc = *((const uint4*)(Ep + (size_t)i1 * 400) + lane);
            float z;
            z = lo2f(a.x)+lo2f(b.x)+lo2f(cc.x)+qv[0]; sum = fmaf(fast_tanh(z), wv[0], sum);
            z = hi2f(a.x)+hi2f(b.x)+hi2f(cc.x)+qv[1]; sum = fmaf(fast_tanh(z), wv[1], sum);
            z = lo2f(a.y)+lo2f(b.y)+lo2f(cc.y)+qv[2]; sum = fmaf(fast_tanh(z), wv[2], sum);
            z = hi2f(a.y)+hi2f(b.y)+hi2f(cc.y)+qv[3]; sum = fmaf(fast_tanh(z), wv[3], sum);
            z = lo2f(a.z)+lo2f(b.z)+lo2f(cc.z)+qv[4]; sum = fmaf(fast_tanh(z), wv[4], sum);
            z = hi2f(a.z)+hi2f(b.z)+hi2f(cc.z)+qv[5]; sum = fmaf(fast_tanh(z), wv[5], sum);
            z = lo2f(a.w)+lo2f(b.w)+lo2f(cc.w)+qv[6]; sum = fmaf(fast_tanh(z), wv[6], sum);
            z = hi2f(a.w)+hi2f(b.w)+hi2f(cc.w)+qv[7]; sum = fmaf(fast_tanh(z), wv[7], sum);
        }
#pragma unroll
        for (int off = 32; off; off >>= 1) sum += __shfl_xor(sum, off);
        if (lane == 0) ctx[(size_t)bt * 100 + l] = sum;
    }
}

// ---------- softmax over T: one wave per (b,l) ----------
__global__ __launch_bounds__(256) void softmax_w(
    const float* __restrict__ ctx, float* __restrict__ attn)
{
    int wid = blockIdx.x * 4 + (threadIdx.x >> 6);   // 0..1599
    int lane = threadIdx.x & 63;
    int b = wid / 100, l = wid - b * 100;
    size_t base = (size_t)b * 128 * 100 + l;
    float v0 = ctx[base + (size_t)lane * 100];
    float v1 = ctx[base + (size_t)(lane + 64) * 100];
    float m = fmaxf(v0, v1);
#pragma unroll
    for (int off = 32; off; off >>= 1) m = fmaxf(m, __shfl_xor(m, off));
    float e0 = __expf(v0 - m), e1 = __expf(v1 - m);
    float s = e0 + e1;
#pragma unroll
    for (int off = 32; off; off >>= 1) s += __shfl_xor(s, off);
    float rs = 1.f / s;
    attn[base + (size_t)lane * 100] = e0 * rs;
    attn[base + (size_t)(lane + 64) * 100] = e1 * rs;
}

// ---------- stage C: weighted re-gather of raw embeddings ----------
__global__ __launch_bounds__(128) void stage_c(
    const float* __restrict__ x, const float* __restrict__ attn,
    const unsigned short* __restrict__ ENb, const unsigned short* __restrict__ EPb,
    float* __restrict__ cv)
{
    __shared__ float at[100];
    __shared__ int idx[300];
    int bt = blockIdx.x, tid = threadIdx.x;
    if (tid < 100) at[tid] = attn[(size_t)bt * 100 + tid];
    const float* xr = x + (size_t)bt * 400 + 100;
    for (int i = tid; i < 300; i += 128) idx[i] = (int)xr[i];
    __syncthreads();
    int d = tid;
    if (d < 100) {
        float as = 0.f, ae = 0.f, ap = 0.f, sa = 0.f;
#pragma unroll 4
        for (int l = 0; l < 100; l++) {
            float a = at[l]; sa += a;
            as = fmaf(a, lo2f(ENb[(size_t)idx[3 * l] * 100 + d]), as);
            ae = fmaf(a, lo2f(ENb[(size_t)idx[3 * l + 2] * 100 + d]), ae);
            ap = fmaf(a, lo2f(EPb[(size_t)idx[3 * l + 1] * 100 + d]), ap);
        }
        float* o = cv + (size_t)bt * 400;
        o[d] = as; o[100 + d] = ae; o[200 + d] = ap;
        o[300 + d] = x[(size_t)bt * 400 + d] * sa;
    }
}

// ---------- X = rnn_in @ Wih.T + biases ----------
__global__ __launch_bounds__(512) void gemm_x(
    const float* __restrict__ x, const float* __restrict__ cv,
    const float* __restrict__ WihT, const float* __restrict__ bih,
    const float* __restrict__ bhh, float* __restrict__ X)
{
    __shared__ float ins[8][500];
    int r0 = blockIdx.x * 8, tid = threadIdx.x;
    for (int i = tid; i < 4000; i += 512) {
        int r = i / 500, k = i - r * 500;
        ins[r][k] = (k < 100) ? x[(size_t)(r0 + r) * 400 + k]
                              : cv[(size_t)(r0 + r) * 400 + (k - 100)];
    }
    __syncthreads();
    int g = tid;
    float acc[8];
#pragma unroll
    for (int r = 0; r < 8; r++) acc[r] = 0.f;
    for (int k4 = 0; k4 < 125; k4++) {
        int k = k4 * 4;
        float w0 = WihT[(size_t)k * 512 + g];
        float w1 = WihT[(size_t)(k + 1) * 512 + g];
        float w2 = WihT[(size_t)(k + 2) * 512 + g];
        float w3 = WihT[(size_t)(k + 3) * 512 + g];
#pragma unroll
        for (int r = 0; r < 8; r++) {
            float4 a = *(const float4*)&ins[r][k];
            acc[r] = fmaf(a.x, w0, fmaf(a.y, w1, fmaf(a.z, w2, fmaf(a.w, w3, acc[r]))));
        }
    }
    float bias = bih[g] + bhh[g];
#pragma unroll
    for (int r = 0; r < 8; r++) X[(size_t)(r0 + r) * 512 + g] = acc[r] + bias;
}

// ---------- LSTM via MFMA, chunked LDS staging, 1 barrier/step ----------
// 8 waves; wave w owns hidden units j in [w*16, w*16+16).
// Tile n (n=0:i 1:f 2:g 3:o) covers gate-cols [n*128 + w*16, +16).
// B-frag: lane(col,kg) holds Whh_bf[g*128 + kk*32 + kg*8 .. +8], g = n*128+w*16+col
// (per-tile mapping identical to the R3 kernel that passed; only col bases moved).
// A-frag row 0 = h; D row 0 -> lanes 0-15 acc[n][0].
// All per-step traffic is LDS-only => the compiler's vmcnt(0) drain at each
// __syncthreads is already satisfied; global loads/stores happen once per
// 16-step chunk (Xs refill / hs flush).
__global__ __launch_bounds__(512, 1) void lstm_k(
    const float* __restrict__ X, const __hip_bfloat16* __restrict__ Whh_bf,
    float* __restrict__ hs)
{
    int b = blockIdx.x, tid = threadIdx.x;
    int wave = tid >> 6, lane = tid & 63;
    int col = lane & 15, kg = lane >> 4;

    short8 bf[4][4];
#pragma unroll
    for (int n = 0; n < 4; n++) {
        int g = n * 128 + wave * 16 + col;
#pragma unroll
        for (int kk = 0; kk < 4; kk++)
            bf[n][kk] = *(const short8*)(Whh_bf + (size_t)g * 128 + kk * 32 + kg * 8);
    }

    __shared__ __hip_bfloat16 h_bf[128];
    __shared__ float Xs[16][512];     // 32 KB: current 16-step X chunk
    __shared__ float hsb_s[16][128];  // 8 KB: h outputs for this chunk
    float c = 0.f;
    if (tid < 128) h_bf[tid] = __float2bfloat16(0.f);
    const float* xb = X + (size_t)b * 128 * 512;
    float* hb = hs + (size_t)b * 128 * 128;
    int j = wave * 16 + (lane & 15);  // hidden unit for lanes<16

    __syncthreads();

    for (int tc = 0; tc < 8; tc++) {
        // ---- refill Xs with steps tc*16 .. tc*16+15 (coalesced, once/chunk) ----
        {
            const float* src = xb + (size_t)tc * 16 * 512 + tid;
#pragma unroll
            for (int k = 0; k < 16; k++) Xs[k][tid] = src[k * 512];
        }
        __syncthreads();   // drains refill loads (and prior chunk's flush stores)

#pragma unroll 1
        for (int ts = 0; ts < 16; ts++) {
            short8 af[4];
            short8 zz = {};
#pragma unroll
            for (int kk = 0; kk < 4; kk++) {
                af[kk] = zz;
                if (col == 0) af[kk] = *(const short8*)(h_bf + kk * 32 + kg * 8);
            }
            f32x4 acc[4];
#pragma unroll
            for (int n = 0; n < 4; n++) acc[n] = (f32x4){0.f, 0.f, 0.f, 0.f};
#pragma unroll
            for (int kk = 0; kk < 4; kk++)
#pragma unroll
                for (int n = 0; n < 4; n++)
                    acc[n] = __builtin_amdgcn_mfma_f32_16x16x32_bf16(af[kk], bf[n][kk], acc[n], 0, 0, 0);

            if (lane < 16) {
                float pi = acc[0][0] + Xs[ts][j];
                float pf = acc[1][0] + Xs[ts][128 + j];
                float pg = acc[2][0] + Xs[ts][256 + j];
                float po = acc[3][0] + Xs[ts][384 + j];
                c = sigm(pf) * c + sigm(pi) * fast_tanh(pg);
                float hn = sigm(po) * fast_tanh(c);
                h_bf[j] = __float2bfloat16(hn);
                hsb_s[ts][j] = hn;
            }
            __syncthreads();   // LDS-only outstanding -> near-free
        }

        // ---- flush hsb_s -> global (fire-and-forget; drained at next refill) ----
        {
            float* dst = hb + (size_t)tc * 16 * 128;
#pragma unroll
            for (int k = 0; k < 4; k++) {
                int i = k * 512 + tid;
                dst[i] = hsb_s[i >> 7][i & 127];
            }
        }
    }
}

__global__ __launch_bounds__(64) void fc_k(
    const float* __restrict__ hs, const float* __restrict__ Wfc,
    const float* __restrict__ bfc, float* __restrict__ out)
{
    int r0 = blockIdx.x * 4, o = threadIdx.x;
    if (o >= 50) return;
    float acc[4] = {0.f, 0.f, 0.f, 0.f};
    for (int j = 0; j < 128; j++) {
        float wv = Wfc[j * 50 + o];
#pragma unroll
        for (int r = 0; r < 4; r++)
            acc[r] = fmaf(hs[(size_t)(r0 + r) * 128 + j], wv, acc[r]);
    }
    float bb = bfc[o];
#pragma unroll
    for (int r = 0; r < 4; r++) out[(size_t)(r0 + r) * 50 + o] = sigm(acc[r] + bb);
}

extern "C" void kernel_launch(void* const* d_in, const int* in_sizes, int n_in,
                              void* d_out, int out_size, void* d_ws, size_t ws_size,
                              hipStream_t stream) {
    const float* x   = (const float*)d_in[0];
    const float* EN  = (const float*)d_in[1];
    const float* EP  = (const float*)d_in[2];
    const float* Wt  = (const float*)d_in[3];
    const float* bt  = (const float*)d_in[4];
    const float* Wa  = (const float*)d_in[5];
    // d_in[6] = b_a: uniform shift along the softmax axis -> cancels, unused.
    const float* Wih = (const float*)d_in[7];
    const float* Whh = (const float*)d_in[8];
    const float* bih = (const float*)d_in[9];
    const float* bhh = (const float*)d_in[10];
    const float* Wfc = (const float*)d_in[11];
    const float* bfc = (const float*)d_in[12];
    float* out = (float*)d_out;

    char* ws = (char*)d_ws;
    size_t off = 0;
    auto alloc = [&](size_t bytes) -> char* {
        char* p = ws + off;
        off = (off + bytes + 255) & ~(size_t)255;
        return p;
    };
    __hip_bfloat16* Es  = (__hip_bfloat16*)alloc((size_t)VOCAB_ * 400 * 2);
    __hip_bfloat16* Ee  = (__hip_bfloat16*)alloc((size_t)VOCAB_ * 400 * 2);
    __hip_bfloat16* Epb = (__hip_bfloat16*)alloc((size_t)VOCAB_ * 400 * 2);
    __hip_bfloat16* ENb = (__hip_bfloat16*)alloc((size_t)VOCAB_ * 100 * 2);
    __hip_bfloat16* EPb = (__hip_bfloat16*)alloc((size_t)VOCAB_ * 100 * 2);
    float* q    = (float*)alloc((size_t)BT_ * 400 * 4);
    float* ctx  = (float*)alloc((size_t)BT_ * 100 * 4);
    float* attn = (float*)alloc((size_t)BT_ * 100 * 4);
    float* cv   = (float*)alloc((size_t)BT_ * 400 * 4);
    float* X    = (float*)alloc((size_t)BT_ * 512 * 4);
    float* hsb  = (float*)alloc((size_t)BT_ * 128 * 4);
    float* WihT = (float*)alloc((size_t)500 * 512 * 4);
    __hip_bfloat16* Whh_bf = (__hip_bfloat16*)alloc((size_t)512 * 128 * 2);

    prep_k<<<1024, 256, 0, stream>>>(EN, EP, Wih, Whh, ENb, EPb, WihT, Whh_bf);
    int egrid = (VOCAB_ + 31) / 32;   // 313
    table_gemm3<<<dim3(egrid, 3), 256, 0, stream>>>(EN, EP, Wt, Es, Ee, Epb);
    table_gemm_q<<<BT_ / 32, 256, 0, stream>>>(x, Wt, bt, q);

    stage_a<<<BT_, 256, 0, stream>>>(x, Es, Ee, Epb, q, Wa, ctx);
    softmax_w<<<400, 256, 0, stream>>>(ctx, attn);
    stage_c<<<BT_, 128, 0, stream>>>(x, attn, (const unsigned short*)ENb,
                                     (const unsigned short*)EPb, cv);
    gemm_x<<<BT_ / 8, 512, 0, stream>>>(x, cv, WihT, bih, bhh, X);
    lstm_k<<<B_, 512, 0, stream>>>(X, Whh_bf, hsb);
    fc_k<<<BT_ / 4, 64, 0, stream>>>(hsb, Wfc, bfc, out);
}